// Round 2
// baseline (8441.679 us; speedup 1.0000x reference)
//
#include <hip/hip_runtime.h>
#include <hip/hip_bf16.h>

// Problem constants (fixed shapes)
#define BATCH 2
#define SEQ   2048
#define EMB   1024
#define DATTN 1024
#define NH    16
#define HD    64
#define MM    (BATCH*SEQ)        // 4096 rows
#define SCALE 0.03125f           // 1/sqrt(1024)

// ---------------- GEMM: C = A @ W^T, A fp32 [M,K], W fp32 [N,K] ----------------
// Stores fp32 into head layout [B, H, S, HD]:  (((b*NH+h)*SEQ)+s)*HD + d
#define BM 64
#define BN 64
#define BK 16

__global__ void gemm_proj_kernel(const float* __restrict__ A,
                                 const float* __restrict__ W,
                                 float* __restrict__ Chead)
{
    const int K = EMB;
    __shared__ float As[BM][BK + 1];
    __shared__ float Bs[BN][BK + 1];
    const int tid = threadIdx.x;
    const int tx = tid & 15, ty = tid >> 4;
    const int m0 = blockIdx.x * BM;
    const int n0 = blockIdx.y * BN;

    float acc[4][4] = {};

    for (int kt = 0; kt < K; kt += BK) {
        // 256 threads load 64x16 tiles (4 consecutive fp32 per thread)
        int idx = tid * 4;
        int row = idx >> 4;      // /16
        int col = idx & 15;      // 0,4,8,12
        float4 av = *(const float4*)(A + (long)(m0 + row) * K + kt + col);
        float4 wv = *(const float4*)(W + (long)(n0 + row) * K + kt + col);
        As[row][col + 0] = av.x; As[row][col + 1] = av.y;
        As[row][col + 2] = av.z; As[row][col + 3] = av.w;
        Bs[row][col + 0] = wv.x; Bs[row][col + 1] = wv.y;
        Bs[row][col + 2] = wv.z; Bs[row][col + 3] = wv.w;
        __syncthreads();

        #pragma unroll
        for (int kk = 0; kk < BK; ++kk) {
            float a[4], b[4];
            #pragma unroll
            for (int r = 0; r < 4; ++r) a[r] = As[ty * 4 + r][kk];
            #pragma unroll
            for (int c = 0; c < 4; ++c) b[c] = Bs[tx * 4 + c][kk];
            #pragma unroll
            for (int r = 0; r < 4; ++r)
                #pragma unroll
                for (int c = 0; c < 4; ++c)
                    acc[r][c] += a[r] * b[c];
        }
        __syncthreads();
    }

    #pragma unroll
    for (int r = 0; r < 4; ++r) {
        const int m = m0 + ty * 4 + r;
        const int b = m >> 11;          // /SEQ
        const int s = m & (SEQ - 1);
        #pragma unroll
        for (int c = 0; c < 4; ++c) {
            const int n = n0 + tx * 4 + c;
            const int h = n >> 6;       // /HD
            const int d = n & (HD - 1);
            Chead[((((long)(b * NH + h)) * SEQ + s) << 6) + d] = acc[r][c];
        }
    }
}

// ---------------- GEMM: out = ctx @ Wo^T, ctx fp32 [M,K], Wo fp32 [N,K], out fp32 ----------------
__global__ void gemm_out_kernel(const float* __restrict__ A,
                                const float* __restrict__ W,
                                float* __restrict__ C)
{
    const int K = DATTN, N = EMB;
    __shared__ float As[BM][BK + 1];
    __shared__ float Bs[BN][BK + 1];
    const int tid = threadIdx.x;
    const int tx = tid & 15, ty = tid >> 4;
    const int m0 = blockIdx.x * BM;
    const int n0 = blockIdx.y * BN;

    float acc[4][4] = {};

    for (int kt = 0; kt < K; kt += BK) {
        int idx = tid * 4;
        int row = idx >> 4;
        int col = idx & 15;
        float4 av = *(const float4*)(A + (long)(m0 + row) * K + kt + col);
        float4 wv = *(const float4*)(W + (long)(n0 + row) * K + kt + col);
        As[row][col + 0] = av.x; As[row][col + 1] = av.y;
        As[row][col + 2] = av.z; As[row][col + 3] = av.w;
        Bs[row][col + 0] = wv.x; Bs[row][col + 1] = wv.y;
        Bs[row][col + 2] = wv.z; Bs[row][col + 3] = wv.w;
        __syncthreads();

        #pragma unroll
        for (int kk = 0; kk < BK; ++kk) {
            float a[4], b[4];
            #pragma unroll
            for (int r = 0; r < 4; ++r) a[r] = As[ty * 4 + r][kk];
            #pragma unroll
            for (int c = 0; c < 4; ++c) b[c] = Bs[tx * 4 + c][kk];
            #pragma unroll
            for (int r = 0; r < 4; ++r)
                #pragma unroll
                for (int c = 0; c < 4; ++c)
                    acc[r][c] += a[r] * b[c];
        }
        __syncthreads();
    }

    #pragma unroll
    for (int r = 0; r < 4; ++r) {
        const int m = m0 + ty * 4 + r;
        #pragma unroll
        for (int c = 0; c < 4; ++c) {
            const int n = n0 + tx * 4 + c;
            C[(long)m * N + n] = acc[r][c];
        }
    }
}

// ---------------- RoPE (in-place on head-layout tensor [B,H,S,HD]) ----------------
__global__ void rope_kernel(float* __restrict__ X)
{
    const int t = blockIdx.x * blockDim.x + threadIdx.x;
    if (t >= BATCH * NH * SEQ * (HD / 2)) return;
    const int p  = t & 31;               // pair index in head dim
    const int s  = (t >> 5) & (SEQ - 1);
    const int bh = t >> 16;              // b*NH + h
    const long base = (((long)bh * SEQ + s) << 6) + p * 2;
    const float inv_freq = powf(10000.0f, -(float)(2 * p) / 64.0f);
    const float ang = (float)s * inv_freq;
    float c, sn;
    __sincosf(ang, &sn, &c);
    const float x0 = X[base], x1 = X[base + 1];
    X[base]     = x0 * c - x1 * sn;
    X[base + 1] = x0 * sn + x1 * c;
}

// ---------------- Attention: one block per (b,h,i) query row ----------------
// mask: allowed j < i (strict), except i==0 -> only j==0
__global__ void attn_kernel(const float* __restrict__ Qh,
                            const float* __restrict__ Kh,
                            const float* __restrict__ Vh,
                            float* __restrict__ ctx)
{
    const int i = blockIdx.x, h = blockIdx.y, b = blockIdx.z;
    const int tid = threadIdx.x;

    __shared__ __align__(16) float sh_q[HD];
    __shared__ float sh_sc[SEQ];
    __shared__ float sh_red[4];
    __shared__ float sh_part[4][HD];

    const long base = ((long)(b * NH + h)) * SEQ * HD;
    const float* qrow = Qh + base + (long)i * HD;
    if (tid < HD) sh_q[tid] = qrow[tid];
    __syncthreads();

    const int limit = (i == 0) ? 1 : i;
    const float* Kbh = Kh + base;

    for (int j = tid; j < limit; j += 256) {
        const float4* k4 = (const float4*)(Kbh + (long)j * HD);
        const float4* q4 = (const float4*)sh_q;
        float dot = 0.f;
        #pragma unroll
        for (int d4 = 0; d4 < HD / 4; ++d4) {
            float4 kv = k4[d4];
            float4 qv = q4[d4];
            dot += kv.x * qv.x + kv.y * qv.y + kv.z * qv.z + kv.w * qv.w;
        }
        sh_sc[j] = dot * SCALE;
    }
    __syncthreads();

    // row max
    float mx = -INFINITY;
    for (int j = tid; j < limit; j += 256) mx = fmaxf(mx, sh_sc[j]);
    #pragma unroll
    for (int o = 32; o > 0; o >>= 1) mx = fmaxf(mx, __shfl_xor(mx, o, 64));
    if ((tid & 63) == 0) sh_red[tid >> 6] = mx;
    __syncthreads();
    mx = fmaxf(fmaxf(sh_red[0], sh_red[1]), fmaxf(sh_red[2], sh_red[3]));
    __syncthreads();

    // exp + sum
    float sum = 0.f;
    for (int j = tid; j < limit; j += 256) {
        float e = __expf(sh_sc[j] - mx);
        sh_sc[j] = e;
        sum += e;
    }
    #pragma unroll
    for (int o = 32; o > 0; o >>= 1) sum += __shfl_xor(sum, o, 64);
    if ((tid & 63) == 0) sh_red[tid >> 6] = sum;
    __syncthreads();
    const float inv = 1.0f / (sh_red[0] + sh_red[1] + sh_red[2] + sh_red[3]);

    // ctx_d = sum_j p_j * V[j][d]
    const int d = tid & 63, g = tid >> 6;
    const float* Vbh = Vh + base;
    float part = 0.f;
    for (int j = g; j < limit; j += 4) part += sh_sc[j] * Vbh[(long)j * HD + d];
    sh_part[g][d] = part;
    __syncthreads();

    if (tid < HD) {
        float tot = (sh_part[0][tid] + sh_part[1][tid] + sh_part[2][tid] + sh_part[3][tid]) * inv;
        // ctx layout [B, S, DATTN]
        ctx[((long)(b * SEQ + i)) * DATTN + h * HD + tid] = tot;
    }
}

extern "C" void kernel_launch(void* const* d_in, const int* in_sizes, int n_in,
                              void* d_out, int out_size, void* d_ws, size_t ws_size,
                              hipStream_t stream) {
    const float* q  = (const float*)d_in[0];
    const float* k  = (const float*)d_in[1];
    const float* v  = (const float*)d_in[2];
    const float* Wq = (const float*)d_in[3];
    const float* Wk = (const float*)d_in[4];
    const float* Wv = (const float*)d_in[5];
    const float* Wo = (const float*)d_in[6];
    float* out = (float*)d_out;

    // workspace layout (fp32): Qh | Kh | Vh | ctx  — 4 x 16 MB = 64 MB
    const long TSZ = (long)BATCH * NH * SEQ * HD;   // 4,194,304
    float* Qh  = (float*)d_ws;
    float* Kh  = Qh + TSZ;
    float* Vh  = Kh + TSZ;
    float* ctx = Vh + TSZ;

    dim3 gemm_grid(MM / BM, DATTN / BN);   // (64, 16)
    gemm_proj_kernel<<<gemm_grid, 256, 0, stream>>>(q, Wq, Qh);
    gemm_proj_kernel<<<gemm_grid, 256, 0, stream>>>(k, Wk, Kh);
    gemm_proj_kernel<<<gemm_grid, 256, 0, stream>>>(v, Wv, Vh);

    const int npairs = BATCH * NH * SEQ * (HD / 2);  // 2,097,152
    rope_kernel<<<(npairs + 255) / 256, 256, 0, stream>>>(Qh);
    rope_kernel<<<(npairs + 255) / 256, 256, 0, stream>>>(Kh);

    attn_kernel<<<dim3(SEQ, NH, BATCH), 256, 0, stream>>>(Qh, Kh, Vh, ctx);

    gemm_out_kernel<<<gemm_grid, 256, 0, stream>>>(ctx, Wo, out);
}

// Round 3
// 5781.284 us; speedup vs baseline: 1.4602x; 1.4602x over previous
//
#include <hip/hip_runtime.h>
#include <hip/hip_bf16.h>

// Problem constants (fixed shapes)
#define BATCH 2
#define SEQ   2048
#define EMB   1024
#define DATTN 1024
#define NH    16
#define HD    64
#define MM    (BATCH*SEQ)        // 4096 rows
#define SCALE 0.03125f           // 1/sqrt(1024)

// ---------------- GEMM: C = A @ W^T, A fp32 [M,K], W fp32 [N,K] ----------------
// Stores fp32 into head layout [B, H, S, HD]:  (((b*NH+h)*SEQ)+s)*HD + d
#define BM 64
#define BN 64
#define BK 16

__global__ void gemm_proj_kernel(const float* __restrict__ A,
                                 const float* __restrict__ W,
                                 float* __restrict__ Chead)
{
    const int K = EMB;
    __shared__ float As[BM][BK + 1];
    __shared__ float Bs[BN][BK + 1];
    const int tid = threadIdx.x;
    const int tx = tid & 15, ty = tid >> 4;
    const int m0 = blockIdx.x * BM;
    const int n0 = blockIdx.y * BN;

    float acc[4][4] = {};

    for (int kt = 0; kt < K; kt += BK) {
        int idx = tid * 4;
        int row = idx >> 4;      // /16
        int col = idx & 15;      // 0,4,8,12
        float4 av = *(const float4*)(A + (long)(m0 + row) * K + kt + col);
        float4 wv = *(const float4*)(W + (long)(n0 + row) * K + kt + col);
        As[row][col + 0] = av.x; As[row][col + 1] = av.y;
        As[row][col + 2] = av.z; As[row][col + 3] = av.w;
        Bs[row][col + 0] = wv.x; Bs[row][col + 1] = wv.y;
        Bs[row][col + 2] = wv.z; Bs[row][col + 3] = wv.w;
        __syncthreads();

        #pragma unroll
        for (int kk = 0; kk < BK; ++kk) {
            float a[4], b[4];
            #pragma unroll
            for (int r = 0; r < 4; ++r) a[r] = As[ty * 4 + r][kk];
            #pragma unroll
            for (int c = 0; c < 4; ++c) b[c] = Bs[tx * 4 + c][kk];
            #pragma unroll
            for (int r = 0; r < 4; ++r)
                #pragma unroll
                for (int c = 0; c < 4; ++c)
                    acc[r][c] += a[r] * b[c];
        }
        __syncthreads();
    }

    #pragma unroll
    for (int r = 0; r < 4; ++r) {
        const int m = m0 + ty * 4 + r;
        const int b = m >> 11;          // /SEQ
        const int s = m & (SEQ - 1);
        #pragma unroll
        for (int c = 0; c < 4; ++c) {
            const int n = n0 + tx * 4 + c;
            const int h = n >> 6;       // /HD
            const int d = n & (HD - 1);
            Chead[((((long)(b * NH + h)) * SEQ + s) << 6) + d] = acc[r][c];
        }
    }
}

// ---------------- GEMM: out = ctx @ Wo^T, ctx fp32 [M,K], Wo fp32 [N,K], out fp32 ----------------
__global__ void gemm_out_kernel(const float* __restrict__ A,
                                const float* __restrict__ W,
                                float* __restrict__ C)
{
    const int K = DATTN, N = EMB;
    __shared__ float As[BM][BK + 1];
    __shared__ float Bs[BN][BK + 1];
    const int tid = threadIdx.x;
    const int tx = tid & 15, ty = tid >> 4;
    const int m0 = blockIdx.x * BM;
    const int n0 = blockIdx.y * BN;

    float acc[4][4] = {};

    for (int kt = 0; kt < K; kt += BK) {
        int idx = tid * 4;
        int row = idx >> 4;
        int col = idx & 15;
        float4 av = *(const float4*)(A + (long)(m0 + row) * K + kt + col);
        float4 wv = *(const float4*)(W + (long)(n0 + row) * K + kt + col);
        As[row][col + 0] = av.x; As[row][col + 1] = av.y;
        As[row][col + 2] = av.z; As[row][col + 3] = av.w;
        Bs[row][col + 0] = wv.x; Bs[row][col + 1] = wv.y;
        Bs[row][col + 2] = wv.z; Bs[row][col + 3] = wv.w;
        __syncthreads();

        #pragma unroll
        for (int kk = 0; kk < BK; ++kk) {
            float a[4], b[4];
            #pragma unroll
            for (int r = 0; r < 4; ++r) a[r] = As[ty * 4 + r][kk];
            #pragma unroll
            for (int c = 0; c < 4; ++c) b[c] = Bs[tx * 4 + c][kk];
            #pragma unroll
            for (int r = 0; r < 4; ++r)
                #pragma unroll
                for (int c = 0; c < 4; ++c)
                    acc[r][c] += a[r] * b[c];
        }
        __syncthreads();
    }

    #pragma unroll
    for (int r = 0; r < 4; ++r) {
        const int m = m0 + ty * 4 + r;
        #pragma unroll
        for (int c = 0; c < 4; ++c) {
            const int n = n0 + tx * 4 + c;
            C[(long)m * N + n] = acc[r][c];
        }
    }
}

// ---------------- RoPE (in-place on head-layout tensor [B,H,S,HD]) ----------------
__global__ void rope_kernel(float* __restrict__ X)
{
    const int t = blockIdx.x * blockDim.x + threadIdx.x;
    if (t >= BATCH * NH * SEQ * (HD / 2)) return;
    const int p  = t & 31;               // pair index in head dim
    const int s  = (t >> 5) & (SEQ - 1);
    const int bh = t >> 16;              // b*NH + h
    const long base = (((long)bh * SEQ + s) << 6) + p * 2;
    const float inv_freq = powf(10000.0f, -(float)(2 * p) / 64.0f);
    const float ang = (float)s * inv_freq;
    float c, sn;
    __sincosf(ang, &sn, &c);
    const float x0 = X[base], x1 = X[base + 1];
    X[base]     = x0 * c - x1 * sn;
    X[base + 1] = x0 * sn + x1 * c;
}

// ---------------- Flash attention: block = (b, h, 128-query tile) ----------------
// 256 threads: tid = 4*qpair + p.  Thread owns query rows (2*qpair, 2*qpair+1)
// and head-dim slice [16p, 16p+16).  K/V staged in LDS in 64-key tiles.
// mask: allowed j < i (strict), except i==0 -> only j==0
#define TQ 128
#define TJ 64

__global__ __launch_bounds__(256, 2)
void flash_attn_kernel(const float* __restrict__ Qh,
                       const float* __restrict__ Kh,
                       const float* __restrict__ Vh,
                       float* __restrict__ ctx)
{
    const int nt = SEQ / TQ;                 // 16 query tiles
    const int t  = nt - 1 - blockIdx.x;      // heavy tiles dispatched first
    const int h  = blockIdx.y, b = blockIdx.z;
    const int tid = threadIdx.x;
    const int p  = tid & 3;
    const int qp = tid >> 2;                 // 0..63
    const int r0 = t * TQ;
    const int i0 = r0 + qp * 2;
    const int i1 = i0 + 1;
    const int dbase = p * 16;

    __shared__ __align__(16) float sk[TJ][HD];
    __shared__ __align__(16) float sv[TJ][HD];

    const long base = ((long)(b * NH + h)) * SEQ * HD;

    // Q fragments in registers: 2 rows x 16 dims
    float q0r[16], q1r[16];
    {
        const float4* qa = (const float4*)(Qh + base + (long)i0 * HD + dbase);
        const float4* qb = (const float4*)(Qh + base + (long)i1 * HD + dbase);
        #pragma unroll
        for (int u = 0; u < 4; ++u) {
            float4 va = qa[u], vb = qb[u];
            q0r[4*u+0] = va.x; q0r[4*u+1] = va.y; q0r[4*u+2] = va.z; q0r[4*u+3] = va.w;
            q1r[4*u+0] = vb.x; q1r[4*u+1] = vb.y; q1r[4*u+2] = vb.z; q1r[4*u+3] = vb.w;
        }
    }

    float acc0[16], acc1[16];
    #pragma unroll
    for (int d = 0; d < 16; ++d) { acc0[d] = 0.f; acc1[d] = 0.f; }
    float m0 = -INFINITY, m1 = -INFINITY, l0 = 0.f, l1 = 0.f;

    const int njt = (r0 + TQ - 2) / TJ + 1;   // = 2t+2 key tiles

    for (int jt = 0; jt < njt; ++jt) {
        const int jbase = jt * TJ;

        __syncthreads();   // protect previous-iteration LDS reads
        #pragma unroll
        for (int u = 0; u < 4; ++u) {
            int idx = u * 1024 + tid * 4;
            int r = idx >> 6, c = idx & 63;
            *(float4*)&sk[r][c] = *(const float4*)(Kh + base + (long)(jbase + r) * HD + c);
            *(float4*)&sv[r][c] = *(const float4*)(Vh + base + (long)(jbase + r) * HD + c);
        }
        __syncthreads();

        const bool masked_tile = (jbase + TJ > r0);

        #pragma unroll
        for (int c4 = 0; c4 < 4; ++c4) {
            float s0[16], s1[16];
            // partial dots over this thread's 16 dims
            #pragma unroll
            for (int kk = 0; kk < 16; ++kk) {
                const int jj = c4 * 16 + kk;
                const float4* kp = (const float4*)&sk[jj][dbase];
                float d0 = 0.f, d1 = 0.f;
                #pragma unroll
                for (int u = 0; u < 4; ++u) {
                    float4 kv = kp[u];
                    d0 += kv.x * q0r[4*u+0] + kv.y * q0r[4*u+1]
                        + kv.z * q0r[4*u+2] + kv.w * q0r[4*u+3];
                    d1 += kv.x * q1r[4*u+0] + kv.y * q1r[4*u+1]
                        + kv.z * q1r[4*u+2] + kv.w * q1r[4*u+3];
                }
                s0[kk] = d0; s1[kk] = d1;
            }
            // reduce partials across the 4 p-lanes (low 2 bits of lane id)
            #pragma unroll
            for (int kk = 0; kk < 16; ++kk) {
                s0[kk] += __shfl_xor(s0[kk], 1, 64);
                s0[kk] += __shfl_xor(s0[kk], 2, 64);
                s1[kk] += __shfl_xor(s1[kk], 1, 64);
                s1[kk] += __shfl_xor(s1[kk], 2, 64);
            }
            // scale + causal mask
            #pragma unroll
            for (int kk = 0; kk < 16; ++kk) {
                const int j = jbase + c4 * 16 + kk;
                s0[kk] *= SCALE; s1[kk] *= SCALE;
                if (masked_tile) {
                    const bool a0 = (j < i0) || (i0 == 0 && j == 0);
                    const bool a1 = (j < i1);
                    if (!a0) s0[kk] = -INFINITY;
                    if (!a1) s1[kk] = -INFINITY;
                }
            }
            // online softmax update
            float mx0 = s0[0], mx1 = s1[0];
            #pragma unroll
            for (int kk = 1; kk < 16; ++kk) { mx0 = fmaxf(mx0, s0[kk]); mx1 = fmaxf(mx1, s1[kk]); }
            const float mn0 = fmaxf(m0, mx0), mn1 = fmaxf(m1, mx1);
            const bool g0 = (mn0 > -INFINITY), g1 = (mn1 > -INFINITY);
            const float a0 = g0 ? __expf(m0 - mn0) : 1.f;   // keeps acc=0,l=0 if untouched
            const float a1 = g1 ? __expf(m1 - mn1) : 1.f;
            float ss0 = 0.f, ss1 = 0.f;
            #pragma unroll
            for (int kk = 0; kk < 16; ++kk) {
                const float e0 = g0 ? __expf(s0[kk] - mn0) : 0.f;
                const float e1 = g1 ? __expf(s1[kk] - mn1) : 0.f;
                s0[kk] = e0; s1[kk] = e1;
                ss0 += e0; ss1 += e1;
            }
            l0 = l0 * a0 + ss0;
            l1 = l1 * a1 + ss1;
            m0 = mn0; m1 = mn1;
            #pragma unroll
            for (int d = 0; d < 16; ++d) { acc0[d] *= a0; acc1[d] *= a1; }
            // PV accumulate (V read shared by both query rows)
            #pragma unroll
            for (int kk = 0; kk < 16; ++kk) {
                const int jj = c4 * 16 + kk;
                const float4* vp = (const float4*)&sv[jj][dbase];
                const float e0 = s0[kk], e1 = s1[kk];
                #pragma unroll
                for (int u = 0; u < 4; ++u) {
                    float4 vv = vp[u];
                    acc0[4*u+0] += e0 * vv.x; acc0[4*u+1] += e0 * vv.y;
                    acc0[4*u+2] += e0 * vv.z; acc0[4*u+3] += e0 * vv.w;
                    acc1[4*u+0] += e1 * vv.x; acc1[4*u+1] += e1 * vv.y;
                    acc1[4*u+2] += e1 * vv.z; acc1[4*u+3] += e1 * vv.w;
                }
            }
        }
    }

    // epilogue: ctx layout [B, S, DATTN]
    const float inv0 = 1.f / l0, inv1 = 1.f / l1;
    float* o0 = ctx + ((long)(b * SEQ + i0)) * DATTN + h * HD + dbase;
    float* o1 = ctx + ((long)(b * SEQ + i1)) * DATTN + h * HD + dbase;
    #pragma unroll
    for (int u = 0; u < 4; ++u) {
        float4 w0, w1;
        w0.x = acc0[4*u+0] * inv0; w0.y = acc0[4*u+1] * inv0;
        w0.z = acc0[4*u+2] * inv0; w0.w = acc0[4*u+3] * inv0;
        w1.x = acc1[4*u+0] * inv1; w1.y = acc1[4*u+1] * inv1;
        w1.z = acc1[4*u+2] * inv1; w1.w = acc1[4*u+3] * inv1;
        *(float4*)(o0 + 4*u) = w0;
        *(float4*)(o1 + 4*u) = w1;
    }
}

extern "C" void kernel_launch(void* const* d_in, const int* in_sizes, int n_in,
                              void* d_out, int out_size, void* d_ws, size_t ws_size,
                              hipStream_t stream) {
    const float* q  = (const float*)d_in[0];
    const float* k  = (const float*)d_in[1];
    const float* v  = (const float*)d_in[2];
    const float* Wq = (const float*)d_in[3];
    const float* Wk = (const float*)d_in[4];
    const float* Wv = (const float*)d_in[5];
    const float* Wo = (const float*)d_in[6];
    float* out = (float*)d_out;

    // workspace layout (fp32): Qh | Kh | Vh | ctx  — 4 x 16 MB = 64 MB
    const long TSZ = (long)BATCH * NH * SEQ * HD;   // 4,194,304
    float* Qh  = (float*)d_ws;
    float* Kh  = Qh + TSZ;
    float* Vh  = Kh + TSZ;
    float* ctx = Vh + TSZ;

    dim3 gemm_grid(MM / BM, DATTN / BN);   // (64, 16)
    gemm_proj_kernel<<<gemm_grid, 256, 0, stream>>>(q, Wq, Qh);
    gemm_proj_kernel<<<gemm_grid, 256, 0, stream>>>(k, Wk, Kh);
    gemm_proj_kernel<<<gemm_grid, 256, 0, stream>>>(v, Wv, Vh);

    const int npairs = BATCH * NH * SEQ * (HD / 2);  // 2,097,152
    rope_kernel<<<(npairs + 255) / 256, 256, 0, stream>>>(Qh);
    rope_kernel<<<(npairs + 255) / 256, 256, 0, stream>>>(Kh);

    flash_attn_kernel<<<dim3(SEQ / TQ, NH, BATCH), 256, 0, stream>>>(Qh, Kh, Vh, ctx);

    gemm_out_kernel<<<gemm_grid, 256, 0, stream>>>(ctx, Wo, out);
}